// Round 14
// baseline (652.644 us; speedup 1.0000x reference)
//
#include <hip/hip_runtime.h>
#include <math.h>

#define NSIZE 20
#define NC 2000
#define H 128
#define NLAYER 3
#define EPB 380
#define NGRP 20
#define CPB 2                        // clones per block (512-thread blocks)

typedef float f32x4 __attribute__((ext_vector_type(4)));
typedef unsigned int u32x4 __attribute__((ext_vector_type(4)));
typedef unsigned short us8 __attribute__((ext_vector_type(8)));
typedef __bf16 bf16x8 __attribute__((ext_vector_type(8)));
typedef unsigned long long u64;

// packed-weight offsets in u32x4 (16B) units
#define OW_E 0
#define OW_K 2048
#define OW_Q 4096
#define OW_V 6144
#define OW_S 8192
#define OW_1 10240
#define OW_2 18432
#define OW_LAYER 26624
#define EA_OFF_B 2097152             // ea_bf16 at +2MB in ws
#define EA_ELEMS 97280000            // 2000*380*128
#define WS_NEED (EA_OFF_B + (size_t)EA_ELEMS*2)

// Per-clone LDS slice (bytes) — R13-proven 16,640 layout; two slices/block.
// Bm (stride 132) aliases qarr (stride 140): needs the R12 race barrier.
#define L_HBF   0        // [20][136] u16   5440
#define L_QARR  5440     // [20][140] u16   5600
#define L_VARR  11040    // [20][140] u16   5600
#define L_X2    5440     // [20][264] u16  10560 (alias, phase D only)
#define L_BM    5440     // [20][132] u16   5280 (alias, B-store -> C-read)
#define L_SLICE 16640
#define L_TOT   (CPB*L_SLICE)        // 33,280 B; 4 blocks/CU -> 133KB < 160KB

static __device__ __forceinline__ unsigned short f2bf(float f){
  unsigned u = __float_as_uint(f);
  u += 0x7fffu + ((u >> 16) & 1u);          // RNE
  return (unsigned short)(u >> 16);
}
static __device__ __forceinline__ float bf2f(unsigned short b){
  return __uint_as_float(((unsigned)b) << 16);
}
static __device__ __forceinline__ unsigned pkbf(float a, float b){
  return (unsigned)f2bf(a) | ((unsigned)f2bf(b) << 16);
}
static __device__ __forceinline__ f32x4 MFMA(u32x4 a, u32x4 b, f32x4 c){
  return __builtin_amdgcn_mfma_f32_16x16x32_bf16(
      __builtin_bit_cast(bf16x8, a), __builtin_bit_cast(bf16x8, b), c, 0, 0, 0);
}
static __device__ __forceinline__ float sigm(float x){
  return __builtin_amdgcn_rcpf(1.f + __expf(-x));
}

// Pack W[K][N] f32 -> bf16 fragments: frag f=(nt*KT+kt), lane l holds
// W[kt*32+(l>>4)*8+j][nt*16+(l&15)]. Serves as B-frag of W and A-frag of W^T.
__global__ __launch_bounds__(256) void pack_weights(
    const float* __restrict__ Wk, const float* __restrict__ Wq,
    const float* __restrict__ Wv, const float* __restrict__ We,
    const float* __restrict__ Ws, const float* __restrict__ W1,
    const float* __restrict__ W2, u32x4* __restrict__ outp)
{
  int l = blockIdx.x / 7, m = blockIdx.x % 7;
  const float* src; int K, N; long base;
  switch(m){
    case 0: src = We + (long)l*H*H;   K=H;   N=H;   base=OW_E; break;
    case 1: src = Wk + (long)l*H*H;   K=H;   N=H;   base=OW_K; break;
    case 2: src = Wq + (long)l*H*H;   K=H;   N=H;   base=OW_Q; break;
    case 3: src = Wv + (long)l*H*H;   K=H;   N=H;   base=OW_V; break;
    case 4: src = Ws + (long)l*H*H;   K=H;   N=H;   base=OW_S; break;
    case 5: src = W1 + (long)l*H*4*H; K=H;   N=4*H; base=OW_1; break;
    default: src = W2 + (long)l*4*H*H; K=4*H; N=H;  base=OW_2; break;
  }
  base += (long)l * OW_LAYER;
  int KT = K/32, NT = N/16;
  int total = KT*NT*64;
  for(int i = threadIdx.x; i < total; i += 256){
    int lane = i & 63, f = i >> 6;
    int kt = f % KT, nt = f / KT;
    int col = nt*16 + (lane & 15);
    int k0 = kt*32 + (lane >> 4)*8;
    us8 v;
    #pragma unroll
    for(int j=0;j<8;++j) v[j] = f2bf(src[(long)(k0+j)*N + col]);
    outp[base + (long)f*64 + lane] = __builtin_bit_cast(u32x4, v);
  }
}

// 512-thread block = 2 clones; each 256-thread half runs one clone in its own
// LDS slice. All barriers are unconditional and identically sequenced in both
// halves, so __syncthreads couples them harmlessly. Tests the workgroup-cap
// hypothesis: 4 WGs/CU x 8 waves = 32 waves (vs 16 with 256-thread blocks).
template<bool EAB>
__global__ __launch_bounds__(512, 4) void moe_gnn(
    const float* __restrict__ x, const float* __restrict__ ea,
    unsigned short* __restrict__ eab,
    const float* __restrict__ g1, const float* __restrict__ b1,
    const float* __restrict__ g2, const float* __restrict__ b2,
    const u32x4* __restrict__ wp, float* __restrict__ out)
{
  __shared__ __align__(16) unsigned char smem[L_TOT];
  const int tid = threadIdx.x;
  const int cid = tid >> 8;          // clone half 0/1
  const int tidh = tid & 255;        // thread within half
  unsigned char* sm = smem + cid*L_SLICE;
  unsigned short* hbf  = (unsigned short*)(sm + L_HBF);   // [20][136]
  unsigned short* x2   = (unsigned short*)(sm + L_X2);    // [20][264]
  unsigned short* qarr = (unsigned short*)(sm + L_QARR);  // [20][140]
  unsigned short* varr = (unsigned short*)(sm + L_VARR);  // [20][140]
  unsigned short* Bm   = (unsigned short*)(sm + L_BM);    // [20][132]

  const int c   = blockIdx.x*CPB + cid;
  const int w   = (tid >> 6) & 3;
  const int l   = tid & 63;
  const int lg  = l >> 4;
  const int l15 = l & 15;
  const long cEPB = (long)c * EPB;
  // clamped fragment rows (nodes 20-31 don't exist; clamped reads produce
  // garbage only in discarded output columns)
  const int rown[2] = { l15, (16 + l15 > 19) ? 19 : 16 + l15 };

  if(EAB){
    // coalesced per-clone conversion: 380*128 f32 -> bf16
    const f32x4* src = (const f32x4*)(ea + cEPB*H);
    u32x4* dst = (u32x4*)(eab + cEPB*H);
    for(int i = tidh; i < EPB*H/8; i += 256){
      f32x4 a = src[2*i], b = src[2*i+1];
      dst[i] = (u32x4){ pkbf(a[0],a[1]), pkbf(a[2],a[3]),
                        pkbf(b[0],b[1]), pkbf(b[2],b[3]) };
    }
  }
  for(int i = tidh; i < NSIZE*H; i += 256){
    int r = i >> 7, cc = i & 127;
    hbf[r*136 + cc] = f2bf(x[((long)c*NSIZE + r)*H + cc]);
  }
  __syncthreads();

  #pragma unroll 1
  for(int layer = 0; layer < NLAYER; ++layer){
    const u32x4* wl = wp + (long)layer*OW_LAYER;
    f32x4 kreg[2][2];                 // k^T in-lane
    f32x4 agg[2][2];                  // skip + sum(msg), in-lane

    // ---- Phase A: swapped node GEMMs; k->regs, skip->agg, q/v->LDS ----
    {
      u32x4 hb[2][4];
      #pragma unroll
      for(int nt=0; nt<2; ++nt)
        #pragma unroll
        for(int kt=0; kt<4; ++kt)
          hb[nt][kt] = *(const u32x4*)&hbf[rown[nt]*136 + kt*32 + lg*8];

      #pragma unroll
      for(int m=0; m<4; ++m){
        const long ow = (m==0?OW_K: m==1?OW_Q: m==2?OW_V: OW_S);
        #pragma unroll
        for(int mt=0; mt<2; ++mt)
          #pragma unroll
          for(int nt=0; nt<2; ++nt){
            f32x4 acc = {0.f,0.f,0.f,0.f};
            #pragma unroll
            for(int kt=0; kt<4; ++kt)
              acc = MFMA(wl[ow + (((2*w+mt)*4)+kt)*64 + l], hb[nt][kt], acc);
            if(m==0) kreg[mt][nt] = acc;
            else if(m==3) agg[mt][nt] = acc;
            else {
              unsigned short* dst = (m==1) ? qarr : varr;
              if(nt==0 || l15 < 4){
                u64 pk = (u64)pkbf(acc[0],acc[1]) | ((u64)pkbf(acc[2],acc[3]) << 32);
                *(u64*)&dst[(nt*16+l15)*140 + (2*w+mt)*16 + lg*4] = pk;
              }
            }
          }
      }
    }
    // no barrier: each wave reads back only its own q/v columns

    // ---- Phase B ----
    {
      // hoisted edge-weight fragments (reused across all 20 groups)
      u32x4 eB[2][4];
      #pragma unroll
      for(int mt=0;mt<2;++mt)
        #pragma unroll
        for(int kt=0;kt<4;++kt)
          eB[mt][kt] = wl[OW_E + ((2*w+mt)*4+kt)*64 + l];

      // main pass: d = l15 in [0,16)
      #pragma unroll 2
      for(int g=0; g<NGRP; ++g){
        bool va = (l15 != g);
        int s = l15 - ((l15 > g) ? 1 : 0);
        long row = cEPB + (long)g*19 + (va ? s : 0);
        u32x4 ef[4];
        if(EAB){
          const unsigned short* ep = eab + row*H + lg*8;
          #pragma unroll
          for(int kt=0;kt<4;++kt) ef[kt] = *(const u32x4*)(ep + kt*32);
        } else {
          const float* ap = ea + row*H + lg*8;
          #pragma unroll
          for(int kt=0;kt<4;++kt){
            f32x4 lo = *(const f32x4*)(ap + kt*32);
            f32x4 hi = *(const f32x4*)(ap + kt*32 + 4);
            ef[kt] = (u32x4){ pkbf(lo[0],lo[1]), pkbf(lo[2],lo[3]),
                              pkbf(hi[0],hi[1]), pkbf(hi[2],hi[3]) };
          }
        }
        #pragma unroll
        for(int mt=0; mt<2; ++mt){
          u64 q8 = *(const u64*)&qarr[g*140 + (2*w+mt)*16 + lg*4];
          u64 v8 = *(const u64*)&varr[g*140 + (2*w+mt)*16 + lg*4];
          f32x4 acc = {0.f,0.f,0.f,0.f};
          #pragma unroll
          for(int kt=0;kt<4;++kt)
            acc = MFMA(eB[mt][kt], ef[kt], acc);
          #pragma unroll
          for(int j=0;j<4;++j){
            float q_ = bf2f((unsigned short)(q8 >> (16*j)));
            float v_ = bf2f((unsigned short)(v8 >> (16*j)));
            float xg = acc[j] + kreg[mt][0][j] + q_;
            float m_ = sigm(xg) * v_;
            agg[mt][0][j] += va ? m_ : 0.f;
          }
        }
      }

      // residue pass: lane l15 = qi*4+di handles (g=qb+qi, d=16+di)
      {
        const int qi = l15 >> 2, di = l15 & 3;
        f32x4 aggR[2];
        aggR[0] = (f32x4){0.f,0.f,0.f,0.f};
        aggR[1] = (f32x4){0.f,0.f,0.f,0.f};
        #pragma unroll 1
        for(int qb=0; qb<NGRP; qb+=4){
          int g = qb + qi;
          int d = 16 + di;
          bool va = (d != g);                 // false only when qb==16 && di==qi
          int s = d - ((d > g) ? 1 : 0);
          long row = cEPB + (long)g*19 + (va ? s : 0);
          u32x4 ef[4];
          if(EAB){
            const unsigned short* ep = eab + row*H + lg*8;
            #pragma unroll
            for(int kt=0;kt<4;++kt) ef[kt] = *(const u32x4*)(ep + kt*32);
          } else {
            const float* ap = ea + row*H + lg*8;
            #pragma unroll
            for(int kt=0;kt<4;++kt){
              f32x4 lo = *(const f32x4*)(ap + kt*32);
              f32x4 hi = *(const f32x4*)(ap + kt*32 + 4);
              ef[kt] = (u32x4){ pkbf(lo[0],lo[1]), pkbf(lo[2],lo[3]),
                                pkbf(hi[0],hi[1]), pkbf(hi[2],hi[3]) };
            }
          }
          #pragma unroll
          for(int mt=0; mt<2; ++mt){
            u64 q8 = *(const u64*)&qarr[g*140 + (2*w+mt)*16 + lg*4];
            u64 v8 = *(const u64*)&varr[g*140 + (2*w+mt)*16 + lg*4];
            f32x4 acc = {0.f,0.f,0.f,0.f};
            #pragma unroll
            for(int kt=0;kt<4;++kt)
              acc = MFMA(eB[mt][kt], ef[kt], acc);
            #pragma unroll
            for(int j=0;j<4;++j){
              float kk = __shfl(kreg[mt][1][j], (lg<<4) | di, 64);
              float q_ = bf2f((unsigned short)(q8 >> (16*j)));
              float v_ = bf2f((unsigned short)(v8 >> (16*j)));
              float xg = acc[j] + kk + q_;
              float m_ = sigm(xg) * v_;
              aggR[mt][j] += va ? m_ : 0.f;
            }
          }
        }
        // reduce over qi (lanes l15^4, l15^8 share di) and add into agg[·][1]
        #pragma unroll
        for(int mt=0; mt<2; ++mt)
          #pragma unroll
          for(int j=0;j<4;++j){
            float t = aggR[mt][j];
            t += __shfl_xor(t, 4, 64);
            t += __shfl_xor(t, 8, 64);
            agg[mt][1][j] += t;
          }
      }

      // RACE FIX (R12): all waves must finish reading qarr/varr before the
      // stride-mismatched Bm alias is written.
      __syncthreads();

      // Bm[d][col] = skip + agg, bf16 (q/v dead now; Bm aliases their region)
      #pragma unroll
      for(int nt=0; nt<2; ++nt)
        if(nt==0 || l15 < 4)
          #pragma unroll
          for(int mt=0; mt<2; ++mt)
            *(u64*)&Bm[(nt*16+l15)*132 + (2*w+mt)*16 + lg*4] =
              (u64)pkbf(agg[mt][nt][0], agg[mt][nt][1]) |
              ((u64)pkbf(agg[mt][nt][2], agg[mt][nt][3]) << 32);
    }
    __syncthreads();

    // ---- Phase C: LN1; reads Bm (bf16), writes hbf = LN1 out ----
    {
      const float* gp = g1 + layer*H; const float* bp = b1 + layer*H;
      float gv0 = gp[l], gv1 = gp[64+l], bv0 = bp[l], bv1 = bp[64+l];
      for(int i=0;i<5;++i){
        int r = w + 4*i;
        float v0 = bf2f(Bm[r*132 + l]), v1 = bf2f(Bm[r*132 + 64 + l]);
        float s = v0+v1;
        #pragma unroll
        for(int m=1;m<64;m<<=1) s += __shfl_xor(s, m, 64);
        float mu = s*(1.f/128.f);
        float d0=v0-mu, d1=v1-mu;
        float qv = d0*d0 + d1*d1;
        #pragma unroll
        for(int m=1;m<64;m<<=1) qv += __shfl_xor(qv, m, 64);
        float rs = rsqrtf(qv*(1.f/128.f) + 1e-5f);
        float y0 = d0*rs*gv0 + bv0;
        float y1 = d1*rs*gv1 + bv1;
        hbf[r*136 + l] = f2bf(y0); hbf[r*136 + 64 + l] = f2bf(y1);
      }
    }
    __syncthreads();

    // ---- Phase D: FFN (two 256-col halves; x2 aliases q/v/Bm region) ----
    {
      u32x4 hb2[2][4];
      #pragma unroll
      for(int nt=0;nt<2;++nt)
        #pragma unroll
        for(int kt=0;kt<4;++kt)
          hb2[nt][kt] = *(const u32x4*)&hbf[rown[nt]*136 + kt*32 + lg*8];
      f32x4 c2[2][2];
      #pragma unroll
      for(int mt=0;mt<2;++mt)
        #pragma unroll
        for(int nt=0;nt<2;++nt)
          c2[mt][nt] = (f32x4){0.f,0.f,0.f,0.f};
      #pragma unroll 1
      for(int hh=0; hh<2; ++hh){
        // W1^T @ h^T -> gelu -> x2[node][localcol]
        for(int i2=0;i2<4;++i2){
          int mtg = hh*16 + w*4 + i2;
          #pragma unroll
          for(int nt=0;nt<2;++nt){
            f32x4 acc = {0.f,0.f,0.f,0.f};
            #pragma unroll
            for(int kt=0;kt<4;++kt)
              acc = MFMA(wl[OW_1 + (mtg*4+kt)*64 + l], hb2[nt][kt], acc);
            float ge[4];
            #pragma unroll
            for(int j=0;j<4;++j){
              float v = acc[j];
              float u = v*(0.7978845608f + 0.0356774081f*v*v);
              ge[j] = v * sigm(2.f*u);
            }
            if(nt==0 || l15 < 4){
              u64 pk = (u64)pkbf(ge[0],ge[1]) | ((u64)pkbf(ge[2],ge[3]) << 32);
              *(u64*)&x2[(nt*16+l15)*264 + (w*4+i2)*16 + lg*4] = pk;
            }
          }
        }
        __syncthreads();
        // W2^T @ x2^T (clamped-row frag reads)
        #pragma unroll
        for(int nt=0;nt<2;++nt){
          #pragma unroll
          for(int kt=0;kt<8;++kt){
            u32x4 xb = *(const u32x4*)&x2[rown[nt]*264 + kt*32 + lg*8];
            #pragma unroll
            for(int mt=0;mt<2;++mt)
              c2[mt][nt] = MFMA(wl[OW_2 + ((2*w+mt)*16 + hh*8 + kt)*64 + l],
                                xb, c2[mt][nt]);
          }
        }
        __syncthreads();
      }
      // residual: hbf[d][col] = out(LN1, already in hbf) + ffn
      #pragma unroll
      for(int nt=0;nt<2;++nt)
        if(nt==0 || l15 < 4)
          #pragma unroll
          for(int mt=0;mt<2;++mt){
            unsigned short* p = &hbf[(nt*16+l15)*136 + (2*w+mt)*16 + lg*4];
            u64 o8 = *(u64*)p;
            float r0 = bf2f((unsigned short)(o8      )) + c2[mt][nt][0];
            float r1 = bf2f((unsigned short)(o8 >> 16)) + c2[mt][nt][1];
            float r2 = bf2f((unsigned short)(o8 >> 32)) + c2[mt][nt][2];
            float r3 = bf2f((unsigned short)(o8 >> 48)) + c2[mt][nt][3];
            *(u64*)p = (u64)pkbf(r0,r1) | ((u64)pkbf(r2,r3) << 32);
          }
    }
    __syncthreads();

    // ---- Phase E: LN2 on hbf in-place; final layer -> d_out ----
    {
      const float* gp = g2 + layer*H; const float* bp = b2 + layer*H;
      float gv0 = gp[l], gv1 = gp[64+l], bv0 = bp[l], bv1 = bp[64+l];
      for(int i=0;i<5;++i){
        int r = w + 4*i;
        float v0 = bf2f(hbf[r*136 + l]), v1 = bf2f(hbf[r*136 + 64 + l]);
        float s = v0+v1;
        #pragma unroll
        for(int m=1;m<64;m<<=1) s += __shfl_xor(s, m, 64);
        float mu = s*(1.f/128.f);
        float d0=v0-mu, d1=v1-mu;
        float qv = d0*d0 + d1*d1;
        #pragma unroll
        for(int m=1;m<64;m<<=1) qv += __shfl_xor(qv, m, 64);
        float rs = rsqrtf(qv*(1.f/128.f) + 1e-5f);
        float y0 = d0*rs*gv0 + bv0;
        float y1 = d1*rs*gv1 + bv1;
        hbf[r*136 + l] = f2bf(y0); hbf[r*136 + 64 + l] = f2bf(y1);
        if(layer == NLAYER-1){
          out[((long)c*NSIZE + r)*H + l]      = y0;
          out[((long)c*NSIZE + r)*H + 64 + l] = y1;
        }
      }
    }
    __syncthreads();
  }
}

extern "C" void kernel_launch(void* const* d_in, const int* in_sizes, int n_in,
                              void* d_out, int out_size, void* d_ws, size_t ws_size,
                              hipStream_t stream) {
  const float* x  = (const float*)d_in[0];
  const float* ea = (const float*)d_in[1];
  const float* Wk = (const float*)d_in[2];
  const float* Wq = (const float*)d_in[3];
  const float* Wv = (const float*)d_in[4];
  const float* We = (const float*)d_in[5];
  const float* Ws = (const float*)d_in[6];
  const float* W1 = (const float*)d_in[7];
  const float* W2 = (const float*)d_in[8];
  const float* g1 = (const float*)d_in[9];
  const float* b1 = (const float*)d_in[10];
  const float* g2 = (const float*)d_in[11];
  const float* b2 = (const float*)d_in[12];
  u32x4* wp = (u32x4*)d_ws;

  hipLaunchKernelGGL(pack_weights, dim3(21), dim3(256), 0, stream,
                     Wk, Wq, Wv, We, Ws, W1, W2, wp);
  if(ws_size >= WS_NEED){
    unsigned short* eab = (unsigned short*)((char*)d_ws + EA_OFF_B);
    hipLaunchKernelGGL(moe_gnn<true>, dim3(NC/CPB), dim3(512), 0, stream,
                       x, ea, eab, g1, b1, g2, b2, wp, (float*)d_out);
  } else {
    hipLaunchKernelGGL(moe_gnn<false>, dim3(NC/CPB), dim3(512), 0, stream,
                       x, ea, (unsigned short*)nullptr,
                       g1, b1, g2, b2, wp, (float*)d_out);
  }
}

// Round 15
// 582.665 us; speedup vs baseline: 1.1201x; 1.1201x over previous
//
#include <hip/hip_runtime.h>
#include <math.h>

#define NSIZE 20
#define NC 2000
#define H 128
#define NLAYER 3
#define EPB 380
#define NGRP 20

typedef float f32x4 __attribute__((ext_vector_type(4)));
typedef unsigned int u32x4 __attribute__((ext_vector_type(4)));
typedef unsigned short us8 __attribute__((ext_vector_type(8)));
typedef __bf16 bf16x8 __attribute__((ext_vector_type(8)));
typedef unsigned long long u64;

// packed-weight offsets in u32x4 (16B) units
#define OW_E 0
#define OW_K 2048
#define OW_Q 4096
#define OW_V 6144
#define OW_S 8192
#define OW_1 10240
#define OW_2 18432
#define OW_LAYER 26624
#define EA_OFF_B 2097152             // ea_bf16 at +2MB in ws
#define EA_ELEMS 97280000            // 2000*380*128
#define WS_NEED (EA_OFF_B + (size_t)EA_ELEMS*2)

// LDS layout (bytes) — R10-proven (best total 604us): f32 Bm, FFN halves.
// LESSONS R13/R14: occupancy is pinned ~45% regardless of LDS (17-36KB),
// VGPR (48-64), block size (256/512) — stop chasing it. This round attacks
// TRAFFIC: R10's FETCH 774MB includes ~360MB eab L3 misses caused by the
// streaming 389MB f32 ea read evicting eab; fix = non-temporal ea loads.
#define L_HBF   0        // [32][136] u16   8704
#define L_X2    8704     // [32][264] u16  16896 (aliases qarr/varr)
#define L_QARR  8704     // [20][140] u16   5600
#define L_VARR  14304    // [20][140] u16   5600
#define L_BM    25600    // [20][132] f32  10560
#define L_TOT   36160

static __device__ __forceinline__ unsigned short f2bf(float f){
  unsigned u = __float_as_uint(f);
  u += 0x7fffu + ((u >> 16) & 1u);          // RNE
  return (unsigned short)(u >> 16);
}
static __device__ __forceinline__ float bf2f(unsigned short b){
  return __uint_as_float(((unsigned)b) << 16);
}
static __device__ __forceinline__ unsigned pkbf(float a, float b){
  return (unsigned)f2bf(a) | ((unsigned)f2bf(b) << 16);
}
static __device__ __forceinline__ f32x4 MFMA(u32x4 a, u32x4 b, f32x4 c){
  return __builtin_amdgcn_mfma_f32_16x16x32_bf16(
      __builtin_bit_cast(bf16x8, a), __builtin_bit_cast(bf16x8, b), c, 0, 0, 0);
}
static __device__ __forceinline__ float sigm(float x){
  return __builtin_amdgcn_rcpf(1.f + __expf(-x));
}

// Pack W[K][N] f32 -> bf16 fragments: frag f=(nt*KT+kt), lane l holds
// W[kt*32+(l>>4)*8+j][nt*16+(l&15)]. Serves as B-frag of W and A-frag of W^T.
__global__ __launch_bounds__(256) void pack_weights(
    const float* __restrict__ Wk, const float* __restrict__ Wq,
    const float* __restrict__ Wv, const float* __restrict__ We,
    const float* __restrict__ Ws, const float* __restrict__ W1,
    const float* __restrict__ W2, u32x4* __restrict__ outp)
{
  int l = blockIdx.x / 7, m = blockIdx.x % 7;
  const float* src; int K, N; long base;
  switch(m){
    case 0: src = We + (long)l*H*H;   K=H;   N=H;   base=OW_E; break;
    case 1: src = Wk + (long)l*H*H;   K=H;   N=H;   base=OW_K; break;
    case 2: src = Wq + (long)l*H*H;   K=H;   N=H;   base=OW_Q; break;
    case 3: src = Wv + (long)l*H*H;   K=H;   N=H;   base=OW_V; break;
    case 4: src = Ws + (long)l*H*H;   K=H;   N=H;   base=OW_S; break;
    case 5: src = W1 + (long)l*H*4*H; K=H;   N=4*H; base=OW_1; break;
    default: src = W2 + (long)l*4*H*H; K=4*H; N=H;  base=OW_2; break;
  }
  base += (long)l * OW_LAYER;
  int KT = K/32, NT = N/16;
  int total = KT*NT*64;
  for(int i = threadIdx.x; i < total; i += 256){
    int lane = i & 63, f = i >> 6;
    int kt = f % KT, nt = f / KT;
    int col = nt*16 + (lane & 15);
    int k0 = kt*32 + (lane >> 4)*8;
    us8 v;
    #pragma unroll
    for(int j=0;j<8;++j) v[j] = f2bf(src[(long)(k0+j)*N + col]);
    outp[base + (long)f*64 + lane] = __builtin_bit_cast(u32x4, v);
  }
}

// One block = one clone. All GEMMs swapped (C^T = W^T @ X^T); node dim in l15.
// Prologue: coalesced per-clone ea f32->bf16 conversion (R10-proven), with
// NON-TEMPORAL ea loads (touch-once; keep the 389MB stream out of L3 so the
// 195MB eab working set stays resident for layers 1-2).
template<bool EAB>
__global__ __launch_bounds__(256, 4) void moe_gnn(
    const float* __restrict__ x, const float* __restrict__ ea,
    unsigned short* __restrict__ eab,
    const float* __restrict__ g1, const float* __restrict__ b1,
    const float* __restrict__ g2, const float* __restrict__ b2,
    const u32x4* __restrict__ wp, float* __restrict__ out)
{
  __shared__ __align__(16) unsigned char smem[L_TOT];
  unsigned short* hbf  = (unsigned short*)(smem + L_HBF);   // [32][136]
  unsigned short* x2   = (unsigned short*)(smem + L_X2);    // [32][264]
  unsigned short* qarr = (unsigned short*)(smem + L_QARR);  // [20][140]
  unsigned short* varr = (unsigned short*)(smem + L_VARR);  // [20][140]
  float*          Bm   = (float*)(smem + L_BM);             // [20][132]

  const int c   = blockIdx.x;
  const int tid = threadIdx.x;
  const int w   = tid >> 6;
  const int l   = tid & 63;
  const int lg  = l >> 4;
  const int l15 = l & 15;
  const long cEPB = (long)c * EPB;

  if(EAB){
    // coalesced per-clone conversion: 380*128 f32 -> bf16 (NT reads)
    const f32x4* src = (const f32x4*)(ea + cEPB*H);
    u32x4* dst = (u32x4*)(eab + cEPB*H);
    for(int i = tid; i < EPB*H/8; i += 256){
      f32x4 a = __builtin_nontemporal_load(&src[2*i]);
      f32x4 b = __builtin_nontemporal_load(&src[2*i+1]);
      dst[i] = (u32x4){ pkbf(a[0],a[1]), pkbf(a[2],a[3]),
                        pkbf(b[0],b[1]), pkbf(b[2],b[3]) };
    }
  }
  for(int i = tid; i < 32*H; i += 256){
    int r = i >> 7, cc = i & 127;
    float v = (r < NSIZE) ? x[((long)c*NSIZE + r)*H + cc] : 0.f;
    hbf[r*136 + cc] = f2bf(v);
  }
  __syncthreads();

  #pragma unroll 1
  for(int layer = 0; layer < NLAYER; ++layer){
    const u32x4* wl = wp + (long)layer*OW_LAYER;
    f32x4 kreg[2][2];                 // k^T in-lane
    f32x4 agg[2][2];                  // skip + sum(msg), in-lane

    // ---- Phase A: swapped node GEMMs; k->regs, skip->agg, q/v->LDS ----
    {
      u32x4 hb[2][4];
      #pragma unroll
      for(int nt=0; nt<2; ++nt)
        #pragma unroll
        for(int kt=0; kt<4; ++kt)
          hb[nt][kt] = *(const u32x4*)&hbf[(nt*16+l15)*136 + kt*32 + lg*8];

      #pragma unroll
      for(int m=0; m<4; ++m){
        const long ow = (m==0?OW_K: m==1?OW_Q: m==2?OW_V: OW_S);
        #pragma unroll
        for(int mt=0; mt<2; ++mt)
          #pragma unroll
          for(int nt=0; nt<2; ++nt){
            f32x4 acc = {0.f,0.f,0.f,0.f};
            #pragma unroll
            for(int kt=0; kt<4; ++kt)
              acc = MFMA(wl[ow + (((2*w+mt)*4)+kt)*64 + l], hb[nt][kt], acc);
            if(m==0) kreg[mt][nt] = acc;
            else if(m==3) agg[mt][nt] = acc;
            else {
              unsigned short* dst = (m==1) ? qarr : varr;
              if(nt==0 || l15 < 4){
                u64 pk = (u64)pkbf(acc[0],acc[1]) | ((u64)pkbf(acc[2],acc[3]) << 32);
                *(u64*)&dst[(nt*16+l15)*140 + (2*w+mt)*16 + lg*4] = pk;
              }
            }
          }
      }
    }
    // no barrier: each wave reads back only its own q/v columns

    // ---- Phase B ----
    {
      // hoisted edge-weight fragments (reused across all 20 groups)
      u32x4 eB[2][4];
      #pragma unroll
      for(int mt=0;mt<2;++mt)
        #pragma unroll
        for(int kt=0;kt<4;++kt)
          eB[mt][kt] = wl[OW_E + ((2*w+mt)*4+kt)*64 + l];

      // main pass: d = l15 in [0,16)
      #pragma unroll 2
      for(int g=0; g<NGRP; ++g){
        bool va = (l15 != g);
        int s = l15 - ((l15 > g) ? 1 : 0);
        long row = cEPB + (long)g*19 + (va ? s : 0);
        u32x4 ef[4];
        if(EAB){
          const unsigned short* ep = eab + row*H + lg*8;
          #pragma unroll
          for(int kt=0;kt<4;++kt) ef[kt] = *(const u32x4*)(ep + kt*32);
        } else {
          const float* ap = ea + row*H + lg*8;
          #pragma unroll
          for(int kt=0;kt<4;++kt){
            f32x4 lo = *(const f32x4*)(ap + kt*32);
            f32x4 hi = *(const f32x4*)(ap + kt*32 + 4);
            ef[kt] = (u32x4){ pkbf(lo[0],lo[1]), pkbf(lo[2],lo[3]),
                              pkbf(hi[0],hi[1]), pkbf(hi[2],hi[3]) };
          }
        }
        #pragma unroll
        for(int mt=0; mt<2; ++mt){
          u64 q8 = *(const u64*)&qarr[g*140 + (2*w+mt)*16 + lg*4];
          u64 v8 = *(const u64*)&varr[g*140 + (2*w+mt)*16 + lg*4];
          f32x4 acc = {0.f,0.f,0.f,0.f};
          #pragma unroll
          for(int kt=0;kt<4;++kt)
            acc = MFMA(eB[mt][kt], ef[kt], acc);
          #pragma unroll
          for(int j=0;j<4;++j){
            float q_ = bf2f((unsigned short)(q8 >> (16*j)));
            float v_ = bf2f((unsigned short)(v8 >> (16*j)));
            float xg = acc[j] + kreg[mt][0][j] + q_;
            float m_ = sigm(xg) * v_;
            agg[mt][0][j] += va ? m_ : 0.f;
          }
        }
      }

      // residue pass: lane l15 = qi*4+di handles (g=qb+qi, d=16+di)
      {
        const int qi = l15 >> 2, di = l15 & 3;
        f32x4 aggR[2];
        aggR[0] = (f32x4){0.f,0.f,0.f,0.f};
        aggR[1] = (f32x4){0.f,0.f,0.f,0.f};
        #pragma unroll 1
        for(int qb=0; qb<NGRP; qb+=4){
          int g = qb + qi;
          int d = 16 + di;
          bool va = (d != g);                 // false only when qb==16 && di==qi
          int s = d - ((d > g) ? 1 : 0);
          long row = cEPB + (long)g*19 + (va ? s : 0);
          u32x4 ef[4];
          if(EAB){
            const unsigned short* ep = eab + row*H + lg*8;
            #pragma unroll
            for(int kt=0;kt<4;++kt) ef[kt] = *(const u32x4*)(ep + kt*32);
          } else {
            const float* ap = ea + row*H + lg*8;
            #pragma unroll
            for(int kt=0;kt<4;++kt){
              f32x4 lo = *(const f32x4*)(ap + kt*32);
              f32x4 hi = *(const f32x4*)(ap + kt*32 + 4);
              ef[kt] = (u32x4){ pkbf(lo[0],lo[1]), pkbf(lo[2],lo[3]),
                                pkbf(hi[0],hi[1]), pkbf(hi[2],hi[3]) };
            }
          }
          #pragma unroll
          for(int mt=0; mt<2; ++mt){
            u64 q8 = *(const u64*)&qarr[g*140 + (2*w+mt)*16 + lg*4];
            u64 v8 = *(const u64*)&varr[g*140 + (2*w+mt)*16 + lg*4];
            f32x4 acc = {0.f,0.f,0.f,0.f};
            #pragma unroll
            for(int kt=0;kt<4;++kt)
              acc = MFMA(eB[mt][kt], ef[kt], acc);
            #pragma unroll
            for(int j=0;j<4;++j){
              float kk = __shfl(kreg[mt][1][j], (lg<<4) | di, 64);
              float q_ = bf2f((unsigned short)(q8 >> (16*j)));
              float v_ = bf2f((unsigned short)(v8 >> (16*j)));
              float xg = acc[j] + kk + q_;
              float m_ = sigm(xg) * v_;
              aggR[mt][j] += va ? m_ : 0.f;
            }
          }
        }
        // reduce over qi (lanes l15^4, l15^8 share di) and add into agg[·][1]
        #pragma unroll
        for(int mt=0; mt<2; ++mt)
          #pragma unroll
          for(int j=0;j<4;++j){
            float t = aggR[mt][j];
            t += __shfl_xor(t, 4, 64);
            t += __shfl_xor(t, 8, 64);
            agg[mt][1][j] += t;
          }
      }

      // Bm[d][col] = skip + agg (single b128 store, own cols)
      #pragma unroll
      for(int nt=0; nt<2; ++nt)
        if(nt==0 || l15 < 4)
          #pragma unroll
          for(int mt=0; mt<2; ++mt)
            *(f32x4*)&Bm[(nt*16+l15)*132 + (2*w+mt)*16 + lg*4] = agg[mt][nt];
    }
    __syncthreads();

    // ---- Phase C: LN1 -> Bm (f32) + hbf (bf16) ----
    {
      const float* gp = g1 + layer*H; const float* bp = b1 + layer*H;
      float gv0 = gp[l], gv1 = gp[64+l], bv0 = bp[l], bv1 = bp[64+l];
      for(int i=0;i<5;++i){
        int r = w + 4*i;
        float v0 = Bm[r*132 + l], v1 = Bm[r*132 + 64 + l];
        float s = v0+v1;
        #pragma unroll
        for(int m=1;m<64;m<<=1) s += __shfl_xor(s, m, 64);
        float mu = s*(1.f/128.f);
        float d0=v0-mu, d1=v1-mu;
        float qv = d0*d0 + d1*d1;
        #pragma unroll
        for(int m=1;m<64;m<<=1) qv += __shfl_xor(qv, m, 64);
        float rs = rsqrtf(qv*(1.f/128.f) + 1e-5f);
        float y0 = d0*rs*gv0 + bv0;
        float y1 = d1*rs*gv1 + bv1;
        Bm[r*132 + l] = y0; Bm[r*132 + 64 + l] = y1;
        hbf[r*136 + l] = f2bf(y0); hbf[r*136 + 64 + l] = f2bf(y1);
      }
    }
    __syncthreads();

    // ---- Phase D: FFN (two 256-col halves; x2 aliases qarr/varr) ----
    {
      u32x4 hb2[2][4];
      #pragma unroll
      for(int nt=0;nt<2;++nt)
        #pragma unroll
        for(int kt=0;kt<4;++kt)
          hb2[nt][kt] = *(const u32x4*)&hbf[(nt*16+l15)*136 + kt*32 + lg*8];
      f32x4 c2[2][2];
      #pragma unroll
      for(int mt=0;mt<2;++mt)
        #pragma unroll
        for(int nt=0;nt<2;++nt)
          c2[mt][nt] = (f32x4){0.f,0.f,0.f,0.f};
      #pragma unroll 1
      for(int hh=0; hh<2; ++hh){
        // W1^T @ h^T -> gelu -> x2[node][localcol]
        for(int i2=0;i2<4;++i2){
          int mtg = hh*16 + w*4 + i2;
          #pragma unroll
          for(int nt=0;nt<2;++nt){
            f32x4 acc = {0.f,0.f,0.f,0.f};
            #pragma unroll
            for(int kt=0;kt<4;++kt)
              acc = MFMA(wl[OW_1 + (mtg*4+kt)*64 + l], hb2[nt][kt], acc);
            float ge[4];
            #pragma unroll
            for(int j=0;j<4;++j){
              float v = acc[j];
              float u = v*(0.7978845608f + 0.0356774081f*v*v);
              ge[j] = v * sigm(2.f*u);
            }
            u64 pk = (u64)pkbf(ge[0],ge[1]) | ((u64)pkbf(ge[2],ge[3]) << 32);
            *(u64*)&x2[(nt*16+l15)*264 + (w*4+i2)*16 + lg*4] = pk;
          }
        }
        __syncthreads();
        // W2^T @ x2^T
        #pragma unroll
        for(int nt=0;nt<2;++nt){
          #pragma unroll
          for(int kt=0;kt<8;++kt){
            u32x4 xb = *(const u32x4*)&x2[(nt*16+l15)*264 + kt*32 + lg*8];
            #pragma unroll
            for(int mt=0;mt<2;++mt)
              c2[mt][nt] = MFMA(wl[OW_2 + ((2*w+mt)*16 + hh*8 + kt)*64 + l],
                                xb, c2[mt][nt]);
          }
        }
        __syncthreads();
      }
      // residual: Bm[d][col] += ffn
      #pragma unroll
      for(int nt=0;nt<2;++nt)
        if(nt==0 || l15 < 4)
          #pragma unroll
          for(int mt=0;mt<2;++mt){
            float* p = &Bm[(nt*16+l15)*132 + (2*w+mt)*16 + lg*4];
            *(f32x4*)p = *(f32x4*)p + c2[mt][nt];
          }
    }
    __syncthreads();

    // ---- Phase E: LN2 -> hbf (next layer); final layer -> d_out (NT) ----
    {
      const float* gp = g2 + layer*H; const float* bp = b2 + layer*H;
      float gv0 = gp[l], gv1 = gp[64+l], bv0 = bp[l], bv1 = bp[64+l];
      for(int i=0;i<5;++i){
        int r = w + 4*i;
        float v0 = Bm[r*132 + l], v1 = Bm[r*132 + 64 + l];
        float s = v0+v1;
        #pragma unroll
        for(int m=1;m<64;m<<=1) s += __shfl_xor(s, m, 64);
        float mu = s*(1.f/128.f);
        float d0=v0-mu, d1=v1-mu;
        float qv = d0*d0 + d1*d1;
        #pragma unroll
        for(int m=1;m<64;m<<=1) qv += __shfl_xor(qv, m, 64);
        float rs = rsqrtf(qv*(1.f/128.f) + 1e-5f);
        float y0 = d0*rs*gv0 + bv0;
        float y1 = d1*rs*gv1 + bv1;
        hbf[r*136 + l] = f2bf(y0); hbf[r*136 + 64 + l] = f2bf(y1);
        if(layer == NLAYER-1){
          __builtin_nontemporal_store(y0, &out[((long)c*NSIZE + r)*H + l]);
          __builtin_nontemporal_store(y1, &out[((long)c*NSIZE + r)*H + 64 + l]);
        }
      }
    }
    __syncthreads();
  }
}

extern "C" void kernel_launch(void* const* d_in, const int* in_sizes, int n_in,
                              void* d_out, int out_size, void* d_ws, size_t ws_size,
                              hipStream_t stream) {
  const float* x  = (const float*)d_in[0];
  const float* ea = (const float*)d_in[1];
  const float* Wk = (const float*)d_in[2];
  const float* Wq = (const float*)d_in[3];
  const float* Wv = (const float*)d_in[4];
  const float* We = (const float*)d_in[5];
  const float* Ws = (const float*)d_in[6];
  const float* W1 = (const float*)d_in[7];
  const float* W2 = (const float*)d_in[8];
  const float* g1 = (const float*)d_in[9];
  const float* b1 = (const float*)d_in[10];
  const float* g2 = (const float*)d_in[11];
  const float* b2 = (const float*)d_in[12];
  u32x4* wp = (u32x4*)d_ws;

  hipLaunchKernelGGL(pack_weights, dim3(21), dim3(256), 0, stream,
                     Wk, Wq, Wv, We, Ws, W1, W2, wp);
  if(ws_size >= WS_NEED){
    unsigned short* eab = (unsigned short*)((char*)d_ws + EA_OFF_B);
    hipLaunchKernelGGL(moe_gnn<true>, dim3(NC), dim3(256), 0, stream,
                       x, ea, eab, g1, b1, g2, b2, wp, (float*)d_out);
  } else {
    hipLaunchKernelGGL(moe_gnn<false>, dim3(NC), dim3(256), 0, stream,
                       x, ea, (unsigned short*)nullptr,
                       g1, b1, g2, b2, wp, (float*)d_out);
  }
}